// Round 16
// baseline (688.440 us; speedup 1.0000x reference)
//
#include <hip/hip_runtime.h>
#include <stdint.h>

#define NB 4
#define CIN 512
#define PIX 2500
#define KTOT 4608
#define NBOX 22500
#define NPRE 6000
#define NPOST 300
#define NWORD 94
#define SCAP 8192

#define O_LOCS   0
#define O_SCORES 360000
#define O_ROIS   540000
#define O_RIDX   544800
#define O_ANCH   546000

// xT geometry: per image, 64 front-slack + 2704 body + 192 back-slack pixel rows, 512 ch fp16
#define XT_ROWS 2960
#define XT_FRONT 64
#define XT_IMG (XT_ROWS * 512)          // fp16 elements per image
#define XT_SPLIT_BYTES ((size_t)NB * XT_IMG * 2)   // 12,124,160

// workspace offsets (bytes)
#define WO_XT1   0ull
#define WO_XT2   12124160ull
#define WO_WSBLK 24248320ull            // fragment-blocked weights, 9,437,184 B
#define WO_FEATP 33685504ull            // 2 ksplits x 4 b x 2500 p x 512 oc fp32 = 40,960,000
#define WO_WT    74645504ull
#define WO_BOXES 74760192ull
#define WO_DKEY  76200192ull
#define WO_BOX6K 76560192ull
#define WO_VALID 76944192ull
#define WO_MASK  0ull                   // aliases xT (dead after conv)

#define FEATP_HALF 5120000              // floats per ksplit

typedef _Float16 h8 __attribute__((ext_vector_type(8)));
typedef float f32x4 __attribute__((ext_vector_type(4)));
typedef unsigned int u32;
typedef unsigned long long u64;

__device__ __forceinline__ float rd_dim(const int* p) {
  int v = *p;
  if (v > 0 && v < 1000000) return (float)v;
  return __int_as_float(v);
}

// ---------------- zero xT (both splits, incl. slack + borders) --------------
__global__ void k_zero(u32* __restrict__ xt) {
  size_t n = (2 * XT_SPLIT_BYTES) / 4;
  for (size_t i = blockIdx.x * 256ull + threadIdx.x; i < n; i += (size_t)gridDim.x * 256)
    xt[i] = 0u;
}

// ---------------- split + transpose x -> xT[b][pix][ic] fp16 hi/lo ---------
__global__ void k_xT(const float* __restrict__ x, _Float16* __restrict__ x1,
                     _Float16* __restrict__ x2) {
  __shared__ float sx[3200];            // [64 ic][50 c]
  int chunk = blockIdx.x, r0 = blockIdx.y, b = blockIdx.z;
  int t = threadIdx.x;
  int ic0 = chunk * 64;
  for (int i = t; i < 3200; i += 256) {
    int icl = i / 50, c = i - icl * 50;
    sx[i] = x[(((size_t)b * 512 + ic0 + icl) * 50 + r0) * 50 + c];
  }
  __syncthreads();
  for (int j = t; j < 3200; j += 256) {
    int c = j >> 6, icl = j & 63;
    float v = sx[icl * 50 + c];
    _Float16 h1 = (_Float16)v;
    _Float16 h2 = (_Float16)(v - (float)h1);
    size_t dst = (size_t)b * XT_IMG + (size_t)(XT_FRONT + (r0 + 1) * 52 + (c + 1)) * 512 + ic0 + icl;
    x1[dst] = h1;
    x2[dst] = h2;
  }
}

// ---------------- weights -> fragment-blocked split-fp16 -------------------
__global__ void k_splitw(const float* __restrict__ w, _Float16* __restrict__ wblk) {
  int n = 4 * 144 * 16 * 512;
  for (int idx = blockIdx.x * 256 + threadIdx.x; idx < n; idx += gridDim.x * 256) {
    int lane8 = idx & 511;
    int l = lane8 >> 3, j = lane8 & 7;
    int reg = (idx >> 9) & 15;
    int t = idx >> 13;                  // mt*144 + ksI
    int ksI = t % 144, mt = t / 144;
    int ocs = reg >> 1, s = reg & 1;
    int oc = mt * 128 + ocs * 16 + (l & 15);
    int k = ksI * 32 + (l >> 4) * 8 + j;
    int tap = k >> 9, ic = k & 511;
    float v = w[((size_t)oc * 512 + ic) * 9 + tap];
    _Float16 h1 = (_Float16)v;
    wblk[idx] = s ? (_Float16)(v - (float)h1) : h1;
  }
}

// ---------------- pack head weights: wt[(c4*56+j)*4+i] = W[j][c4*4+i] ------
__global__ void k_wt(const float* __restrict__ loc_w, const float* __restrict__ score_w,
                     float* __restrict__ wt) {
  int idx = blockIdx.x * 256 + threadIdx.x;
  if (idx >= 128 * 56 * 4) return;
  int i = idx & 3, j = (idx >> 2) % 56, c4 = idx / 224;
  int c = c4 * 4 + i;
  float v = 0.f;
  if (j < 36) v = loc_w[(size_t)j * 512 + c];
  else if (j < 54) v = score_w[(size_t)(j - 36) * 512 + c];
  wt[idx] = v;
}

// ---------------- conv: pure-register GEMM, no LDS, no barrier -------------
// Each wave owns a private 64oc x 64px tile; A and B fragments load DIRECTLY
// to VGPRs (the LDS round-trip only existed for inter-wave B sharing). The
// compiler register-tracks all loads and software-pipelines with precise
// counted vmcnt - the structural barrier-drain of the gll16 path is gone.
__global__ __launch_bounds__(128, 2) void k_conv(
    const _Float16* __restrict__ xs1, const _Float16* __restrict__ xs2,
    const _Float16* __restrict__ wsBlk,
    float* __restrict__ featP) {
  int id = blockIdx.x;
  int bz = id & 7;                      // XCD-pinned (b,ks)
  int inner = id >> 3;                  // 0..175
  int st = inner / 88;                  // mt supertile 0..1
  int idx2 = inner - st * 88;           // 0..87
  int nt = idx2 >> 1;                   // 0..43 (64px tiles)
  int mt = st * 2 + (idx2 & 1);         // 0..3 (128oc pair)
  int b = bz >> 1, ks = bz & 1;
  int t = threadIdx.x, lane = t & 63, w = t >> 6;   // w in {0,1}: oc-half
  int nb = nt * 64;
  int l15 = lane & 15, l4 = lane >> 4;
  const _Float16* xi1 = xs1 + (size_t)b * XT_IMG + (size_t)XT_FRONT * 512;
  const _Float16* xi2 = xs2 + (size_t)b * XT_IMG + (size_t)XT_FRONT * 512;
  const _Float16* wbase = wsBlk + ((size_t)(mt * 144 + ks * 72) * 16 + w * 8) * 512 + lane * 8;

  f32x4 acc[4][4];                      // [mf][nf]
#pragma unroll
  for (int i = 0; i < 4; i++)
#pragma unroll
    for (int j = 0; j < 4; j++)
      acc[i][j] = (f32x4){0.f, 0.f, 0.f, 0.f};

  auto loadA = [&](int kk, h8* a) {     // 8 frags (mf*2+s), each 1KB contiguous
    const _Float16* p = wbase + (size_t)kk * 16 * 512;
#pragma unroll
    for (int u = 0; u < 8; u++) a[u] = *(const h8*)(p + u * 512);
  };
  auto loadB = [&](int kk, h8* bf) {    // 8 frags (nf*2+s), gll16-source addrs
    int kg = ks * 2304 + kk * 32;
    int tap = kg >> 9, ic0 = kg & 511;
    int sh = (tap / 3 - 1) * 52 + (tap % 3) - 1;
#pragma unroll
    for (int nf = 0; nf < 4; nf++) {
      ptrdiff_t off = (ptrdiff_t)(nb + nf * 16 + l15 + sh) * 512 + ic0 + l4 * 8;
      bf[nf * 2 + 0] = *(const h8*)(xi1 + off);
      bf[nf * 2 + 1] = *(const h8*)(xi2 + off);
    }
  };
  auto compute = [&](const h8* a, const h8* bf) {
#pragma unroll
    for (int nf = 0; nf < 4; nf++) {
      h8 b0 = bf[nf * 2 + 0], b1 = bf[nf * 2 + 1];
#pragma unroll
      for (int mf = 0; mf < 4; mf++) {
        acc[mf][nf] = __builtin_amdgcn_mfma_f32_16x16x32_f16(a[mf * 2 + 0], b0, acc[mf][nf], 0, 0, 0);
        acc[mf][nf] = __builtin_amdgcn_mfma_f32_16x16x32_f16(a[mf * 2 + 0], b1, acc[mf][nf], 0, 0, 0);
        acc[mf][nf] = __builtin_amdgcn_mfma_f32_16x16x32_f16(a[mf * 2 + 1], b0, acc[mf][nf], 0, 0, 0);
      }
    }
  };

  h8 aA[8], bA[8], aB[8], bB[8];
  loadA(0, aA);
  loadB(0, bA);
#pragma unroll 1
  for (int kp = 0; kp < 36; kp++) {
    int kk = 2 * kp;
    loadA(kk + 1, aB);
    loadB(kk + 1, bB);
    compute(aA, bA);
    if (kp < 35) {
      loadA(kk + 2, aA);
      loadB(kk + 2, bA);
    }
    compute(aB, bB);
  }

  // C layout (16x16): col = lane&15 (pix), row = (lane>>4)*4 + reg (oc)
  float* fp = featP + (size_t)ks * FEATP_HALF;
#pragma unroll
  for (int nf = 0; nf < 4; nf++) {
    int q = nb + nf * 16 + l15;
    int r = q / 52, c = q - r * 52;
    if (r >= 1 && r <= 50 && c >= 1 && c <= 50) {
      int p = (r - 1) * 50 + (c - 1);
      size_t base = ((size_t)b * PIX + p) * 512;
#pragma unroll
      for (int mf = 0; mf < 4; mf++) {
        int oc0 = mt * 128 + w * 64 + mf * 16 + l4 * 4;
        *(float4*)&fp[base + oc0] = make_float4(acc[mf][nf][0], acc[mf][nf][1],
                                                acc[mf][nf][2], acc[mf][nf][3]);
      }
    }
  }
}

// ---------------- heads: sum partials + bias + relu, 54 dots, decode -------
__global__ __launch_bounds__(256) void k_heads(const float* __restrict__ featP,
                                               const float* __restrict__ wt4,
                                               const float* __restrict__ conv_b,
                                               const float* __restrict__ loc_b,
                                               const float* __restrict__ score_b,
                                               const int* __restrict__ ihp,
                                               const int* __restrict__ iwp,
                                               float* __restrict__ out,
                                               float* __restrict__ boxes,
                                               uint32_t* __restrict__ dkey) {
  int wid = blockIdx.x * 4 + (threadIdx.x >> 6);
  if (wid >= NB * PIX) return;
  int lane = threadIdx.x & 63;
  int b = wid / PIX, p = wid % PIX;
  int row = lane < 54 ? lane : 54;
  const float* f0 = featP + ((size_t)b * PIX + p) * 512;
  const float* f1 = f0 + FEATP_HALF;
  float acc = 0.f;
  for (int c4 = 0; c4 < 128; c4++) {
    float4 u = *(const float4*)(f0 + c4 * 4);
    float4 v = *(const float4*)(f1 + c4 * 4);
    float4 bb = *(const float4*)(conv_b + c4 * 4);
    float4 wv = *(const float4*)(wt4 + ((size_t)c4 * 56 + row) * 4);
    acc += fmaxf(u.x + v.x + bb.x, 0.f) * wv.x;
    acc += fmaxf(u.y + v.y + bb.y, 0.f) * wv.y;
    acc += fmaxf(u.z + v.z + bb.z, 0.f) * wv.z;
    acc += fmaxf(u.w + v.w + bb.w, 0.f) * wv.w;
  }
  float bi = 0.f;
  if (lane < 36) bi = loc_b[lane];
  else if (lane < 54) bi = score_b[lane - 36];
  acc += bi;
  if (lane < 36) out[O_LOCS + (size_t)b * 90000 + (size_t)p * 36 + lane] = acc;
  else if (lane < 54) out[O_SCORES + (size_t)b * 45000 + (size_t)p * 18 + (lane - 36)] = acc;

  float imgH = rd_dim(ihp), imgW = rd_dim(iwp);
  int gy = p % 50, gx = p / 50;           // transposed-anchor pairing (meshgrid 'ij')
  float sy = 16.f * gy, sx = 16.f * gx;

  int a9 = (lane < 9) ? lane : 0;
  float dy  = __shfl(acc, a9 * 4 + 0);
  float dxv = __shfl(acc, a9 * 4 + 1);
  float dh  = __shfl(acc, a9 * 4 + 2);
  float dw  = __shfl(acc, a9 * 4 + 3);
  float l0  = __shfl(acc, 36 + a9 * 2);
  float l1  = __shfl(acc, 36 + a9 * 2 + 1);

  {
    float rr = (a9 < 3) ? 0.5f : (a9 < 6 ? 1.f : 2.f);
    int si = a9 % 3;
    float ssc = (si == 0) ? 8.f : (si == 1 ? 16.f : 32.f);
    float hb = 16.f * ssc * sqrtf(rr);
    float wb = 16.f * ssc * sqrtf(1.f / rr);
    float ay1 = (8.f - hb * 0.5f) + sy;
    float ax1 = (8.f - wb * 0.5f) + sx;
    float ay2 = (8.f + hb * 0.5f) + sy;
    float ax2 = (8.f + wb * 0.5f) + sx;
    float h = ay2 - ay1, w2d = ax2 - ax1;
    float cy = ay1 + 0.5f * h, cx = ax1 + 0.5f * w2d;
    float cy2 = dy * h + cy, cx2 = dxv * w2d + cx;
    float h2 = expf(dh) * h, ww2 = expf(dw) * w2d;
    float y1 = cy2 - 0.5f * h2, x1 = cx2 - 0.5f * ww2;
    float y2 = cy2 + 0.5f * h2, x2 = cx2 + 0.5f * ww2;
    y1 = fminf(fmaxf(y1, 0.f), imgH);
    x1 = fminf(fmaxf(x1, 0.f), imgW);
    y2 = fminf(fmaxf(y2, 0.f), imgH);
    x2 = fminf(fmaxf(x2, 0.f), imgW);
    bool valid = (y2 - y1 >= 16.f) && (x2 - x1 >= 16.f);
    float m = fmaxf(l0, l1);
    float e0 = expf(l0 - m), e1 = expf(l1 - m);
    float fg = e1 / (e0 + e1);
    float scv = valid ? fg : -INFINITY;
    if (lane < 9) {
      size_t k = (size_t)b * NBOX + (size_t)p * 9 + a9;
      *(float4*)(boxes + k * 4) = make_float4(y1, x1, y2, x2);
      uint32_t u = __float_as_uint(scv);
      uint32_t f2 = (u >> 31) ? ~u : (u | 0x80000000u);
      dkey[k] = ~f2;   // ascending d == descending score
    }
  }
  if (b == 0 && lane < 36) {
    int aa = lane >> 2, dd = lane & 3;
    float rr2 = (aa < 3) ? 0.5f : (aa < 6 ? 1.f : 2.f);
    int si2 = aa % 3;
    float ss2 = (si2 == 0) ? 8.f : (si2 == 1 ? 16.f : 32.f);
    float hb2 = 16.f * ss2 * sqrtf(rr2);
    float wb2 = 16.f * ss2 * sqrtf(1.f / rr2);
    float v;
    if (dd == 0) v = (8.f - hb2 * 0.5f) + sy;
    else if (dd == 1) v = (8.f - wb2 * 0.5f) + sx;
    else if (dd == 2) v = (8.f + hb2 * 0.5f) + sy;
    else v = (8.f + wb2 * 0.5f) + sx;
    out[O_ANCH + (size_t)p * 36 + lane] = v;
  }
}

// ---------------- exact top-6000: radix-select + index-ordered compaction
//                  + stable 4-bit LDS radix sort (parallel prefix scans) ----
__global__ void k_topk(const uint32_t* __restrict__ dkey, const float* __restrict__ boxes,
                       float* __restrict__ box6k,
                       unsigned long long* __restrict__ validm) {
  extern __shared__ char smem[];
  u64* cand = (u64*)smem;                       // 8192 x u64
  u64* alt  = (u64*)(smem + 65536);             // 8192 x u64 (ping-pong)
  u32* hcnt = (u32*)(smem + 131072);            // [128 units][16 digits]
  u32* wc     = (u32*)(smem + 139264);          // 16 wave counts
  u32* digTot = wc + 16;
  u32* digBase = digTot + 16;
  u32* msc = digBase + 16;                      // scalars
  u32* histw = (u32*)(smem + 65536);            // select-phase [16][256] (aliases alt)
  u32* hist = histw + 4096;                     // [256]
  int b = blockIdx.x, tid = threadIdx.x;
  int wq = tid >> 6, l = tid & 63;
  const uint32_t* dk = dkey + (size_t)b * NBOX;

  // ---- radix-select Dstar (4 byte passes, per-wave histograms) ----
  uint32_t P = 0, need = NPRE;
  for (int pass = 0; pass < 4; pass++) {
    int sh = 24 - 8 * pass;
    for (int i = tid; i < 16 * 256; i += 1024) histw[i] = 0;
    __syncthreads();
    for (int i = tid; i < NBOX; i += 1024) {
      uint32_t d = dk[i];
      bool match = (((uint64_t)d >> (sh + 8)) == ((uint64_t)P >> (sh + 8)));
      if (match) atomicAdd(&histw[wq * 256 + ((d >> sh) & 255u)], 1u);
    }
    __syncthreads();
    for (int bin = tid; bin < 256; bin += 1024) {
      uint32_t s = 0;
#pragma unroll
      for (int q = 0; q < 16; q++) s += histw[q * 256 + bin];
      hist[bin] = s;
    }
    __syncthreads();
    // wave 0: parallel threshold find (v* = first bin with inclusive >= need)
    if (tid < 64) {
      uint32_t h0 = hist[l * 4 + 0], h1 = hist[l * 4 + 1];
      uint32_t h2 = hist[l * 4 + 2], h3 = hist[l * 4 + 3];
      uint32_t p1 = h0, p2 = h0 + h1, p3 = p2 + h2, p4 = p3 + h3;
      uint32_t s = p4;
#pragma unroll
      for (int dd = 1; dd < 64; dd <<= 1) { uint32_t v = __shfl_up(s, dd); if (l >= dd) s += v; }
      uint32_t excl = s - p4;
      uint32_t i0 = excl + p1, i1 = excl + p2, i2 = excl + p3, i3 = excl + p4;
      int local = 4;
      if (i0 >= need) local = 0;
      else if (i1 >= need) local = 1;
      else if (i2 >= need) local = 2;
      else if (i3 >= need) local = 3;
      u64 bal = __ballot(local < 4);
      int lw = bal ? __builtin_ctzll(bal) : 63;
      if (l == lw) {
        if (local < 4) {
          msc[0] = (uint32_t)(l * 4 + local);
          msc[1] = (local == 0) ? excl : (local == 1) ? i0 : (local == 2) ? i1 : i2;
        } else {                        // no crossing: v=255, cum=prefixExcl(255)
          msc[0] = 255u;
          msc[1] = i2;
        }
      }
    }
    __syncthreads();
    need -= msc[1];
    P |= msc[0] << sh;
    __syncthreads();
  }
  uint32_t Dstar = P;

  // ---- index-ordered compaction: cand[] ascending by original index ----
  if (tid == 0) msc[2] = 0;
  __syncthreads();
  for (int c = 0; c < 22; c++) {
    int i = c * 1024 + tid;
    uint32_t d = (i < NBOX) ? dk[i] : 0xFFFFFFFFu;
    bool pred = (i < NBOX) && (d <= Dstar);
    u64 bal = __ballot(pred);
    uint32_t rank = (uint32_t)__popcll(bal & ((1ull << l) - 1ull));
    __syncthreads();                    // prior chunk's wc reads complete
    if (l == 0) wc[wq] = (uint32_t)__popcll(bal);
    __syncthreads();
    if (tid < 64) {                     // wave 0: scan 16 wave counts
      uint32_t v = (l < 16) ? wc[l] : 0u;
      uint32_t s = v;
#pragma unroll
      for (int dd = 1; dd < 16; dd <<= 1) { uint32_t t2 = __shfl_up(s, dd); if (l >= dd) s += t2; }
      uint32_t base0 = msc[2];
      if (l < 16) wc[l] = base0 + s - v;
      if (l == 15) msc[2] = base0 + s;
    }
    __syncthreads();
    if (pred) {
      uint32_t pos = wc[wq] + rank;
      if (pos < SCAP) cand[pos] = ((u64)d << 32) | (uint32_t)i;
    }
  }
  __syncthreads();
  uint32_t cnt = msc[2] < SCAP ? msc[2] : SCAP;
  for (int i = (int)cnt + tid; i < SCAP; i += 1024) cand[i] = ~0ull;
  __syncthreads();

  // ---- stable radix sort on d (8 x 4-bit LSB->MSB); idx order preserved ----
  u64* src = cand;
  u64* dst = alt;
  for (int pass = 0; pass < 8; pass++) {
    int sh = 32 + pass * 4;
    for (int i = tid; i < 2048; i += 1024) hcnt[i] = 0;
    __syncthreads();
    for (int c = 0; c < 8; c++) {
      int i = c * 1024 + tid;
      uint32_t dig = (uint32_t)(src[i] >> sh) & 15u;
      u64 m = ~0ull;
#pragma unroll
      for (int bit = 0; bit < 4; bit++) {
        u64 bb = __ballot((dig >> bit) & 1u);
        m &= ((dig >> bit) & 1u) ? bb : ~bb;
      }
      if (l == __builtin_ctzll(m)) hcnt[(i >> 6) * 16 + dig] = (uint32_t)__popcll(m);
    }
    __syncthreads();
    // wave wq scans digit wq's 128 unit counts (parallel over 16 waves)
    {
      int d = wq;
      uint32_t cl = hcnt[l * 16 + d];
      uint32_t ch = hcnt[(l + 64) * 16 + d];
      uint32_t s = cl;
#pragma unroll
      for (int dd = 1; dd < 64; dd <<= 1) { uint32_t v = __shfl_up(s, dd); if (l >= dd) s += v; }
      uint32_t tl = __shfl(s, 63);
      uint32_t el = s - cl;
      uint32_t s2 = ch;
#pragma unroll
      for (int dd = 1; dd < 64; dd <<= 1) { uint32_t v = __shfl_up(s2, dd); if (l >= dd) s2 += v; }
      uint32_t th = __shfl(s2, 63);
      uint32_t eh = tl + (s2 - ch);
      hcnt[l * 16 + d] = el;
      hcnt[(l + 64) * 16 + d] = eh;
      if (l == 0) digTot[d] = tl + th;
    }
    __syncthreads();
    if (tid == 0) {
      uint32_t basev = 0;
      for (int d2 = 0; d2 < 16; d2++) { digBase[d2] = basev; basev += digTot[d2]; }
    }
    __syncthreads();
    for (int c = 0; c < 8; c++) {
      int i = c * 1024 + tid;
      u64 key = src[i];
      uint32_t dig = (uint32_t)(key >> sh) & 15u;
      u64 m = ~0ull;
#pragma unroll
      for (int bit = 0; bit < 4; bit++) {
        u64 bb = __ballot((dig >> bit) & 1u);
        m &= ((dig >> bit) & 1u) ? bb : ~bb;
      }
      uint32_t rank = (uint32_t)__popcll(m & ((1ull << l) - 1ull));
      uint32_t dpos = digBase[dig] + hcnt[(i >> 6) * 16 + dig] + rank;
      dst[dpos] = key;
    }
    __syncthreads();
    u64* tmp = src; src = dst; dst = tmp;
  }

  for (int r = tid; r < NPRE; r += 1024) {
    u64 kk = cand[r];
    uint32_t idx = (uint32_t)kk;
    float4 bx = *(const float4*)(boxes + ((size_t)b * NBOX + idx) * 4);
    *(float4*)(box6k + ((size_t)b * NPRE + r) * 4) = bx;
  }
  for (int wi = tid; wi < NWORD; wi += 1024) {
    unsigned long long m = 0ull;
    for (int bb = 0; bb < 64; bb++) {
      int r = wi * 64 + bb;
      if (r < NPRE) {
        uint32_t d = (uint32_t)(cand[r] >> 32);
        if (d < 0xFF800000u) m |= (1ull << bb);   // score > -inf
      }
    }
    validm[b * NWORD + wi] = m;
  }
}

// ---------------- NMS suppression bitmask (upper-triangle words only) ------
__global__ __launch_bounds__(256) void k_mask(const float* __restrict__ box6k,
                                              unsigned long long* __restrict__ mask) {
  int b = blockIdx.z, it = blockIdx.x, wt = blockIdx.y;
  int t = threadIdx.x;
  int il = t & 31, wl = t >> 5;
  if (wt * 512 + 511 <= it * 32) return;   // fully below diagonal: never read
  __shared__ float bi[32][4];
  __shared__ float bj[512][4];
  if (t < 128) {
    int ii = it * 32 + (t >> 2);
    if (ii > NPRE - 1) ii = NPRE - 1;
    bi[t >> 2][t & 3] = box6k[((size_t)b * NPRE + ii) * 4 + (t & 3)];
  }
#pragma unroll
  for (int q = 0; q < 2; q++) {
    int v = t + 256 * q;
    int jg = wt * 512 + v;
    float4 f = make_float4(0.f, 0.f, 0.f, 0.f);
    if (jg < NPRE) f = *(const float4*)(box6k + ((size_t)b * NPRE + jg) * 4);
    *(float4*)&bj[v][0] = f;
  }
  __syncthreads();
  int i = it * 32 + il;
  int w = wt * 8 + wl;
  if (i >= NPRE || w >= NWORD) return;
  float y1 = bi[il][0], x1 = bi[il][1], y2 = bi[il][2], x2 = bi[il][3];
  float ar = (y2 - y1) * (x2 - x1);
  unsigned long long m = 0ull;
  int jbase = w * 64;
  for (int jj = 0; jj < 64; jj++) {
    int j = jbase + jj;
    int js = wl * 64 + jj;
    float jy1 = bj[js][0], jx1 = bj[js][1], jy2 = bj[js][2], jx2 = bj[js][3];
    float tlY = fmaxf(y1, jy1), tlX = fmaxf(x1, jx1);
    float brY = fminf(y2, jy2), brX = fminf(x2, jx2);
    float ih = fmaxf(brY - tlY, 0.f), iw2 = fmaxf(brX - tlX, 0.f);
    float inter = ih * iw2;
    float arj = (jy2 - jy1) * (jx2 - jx1);
    float iou = inter / (ar + arj - inter);
    if (iou > 0.7f && j > i && j < NPRE) m |= (1ull << jj);
  }
  mask[((size_t)b * NPRE + i) * NWORD + w] = m;
}

// ---------------- NMS scan: word-aligned windows + 2-deep row prefetch -----
__global__ void k_scan(const unsigned long long* __restrict__ mask,
                       const unsigned long long* __restrict__ validm,
                       const float* __restrict__ box6k, float* __restrict__ out) {
  int b = blockIdx.x;
  int lane = threadIdx.x;               // 64 threads = 1 wave
  const unsigned long long* mb = mask + (size_t)b * NPRE * NWORD;
  u64 a0 = (lane < NWORD) ? validm[b * NWORD + lane] : 0ull;
  u64 a1 = (lane + 64 < NWORD) ? validm[b * NWORD + lane + 64] : 0ull;
  __shared__ int keptIdx[NPOST];
  int cnt = 0;
  bool done = false;
  u64 rowCur = mb[(size_t)lane * NWORD + 0];             // word 0 rows
  u64 rowN1 = mb[(size_t)(64 + lane) * NWORD + 1];       // word 1 rows
  for (int w = 0; w < NWORD && !done; w++) {
    // prefetch word w+2's in-word rows (static, independent of alive chain)
    u64 rowN2 = 0ull;
    if (w + 2 < NWORD) {
      int i2 = (w + 2) * 64 + lane;
      if (i2 < NPRE) rowN2 = mb[(size_t)i2 * NWORD + (w + 2)];
    }
    u64 alive = (w < 64) ? __shfl(a0, w) : __shfl(a1, w - 64);
    if (alive) {
      u64 keep = 0ull;
      while (alive) {
        int q = __builtin_ctzll(alive);
        alive &= alive - 1;
        keep |= (1ull << q);
        if (lane == 0) keptIdx[cnt] = w * 64 + q;
        cnt++;
        if (cnt >= NPOST) { done = true; break; }
        alive &= ~__shfl(rowCur, q);    // forward in-word suppression
      }
      if (w < 64) { if (lane == w) a0 = 0ull; }
      else        { if (lane == w - 64) a1 = 0ull; }
      if (!done) {
        while (keep) {
          u64 or0 = 0ull, or1 = 0ull;
#pragma unroll
          for (int z = 0; z < 8; z++) {
            if (keep) {
              int q = __builtin_ctzll(keep);
              keep &= keep - 1;
              int ki = w * 64 + q;
              u64 m0 = (lane < NWORD && lane > w) ? mb[(size_t)ki * NWORD + lane] : 0ull;
              u64 m1 = (lane + 64 < NWORD && lane + 64 > w) ? mb[(size_t)ki * NWORD + 64 + lane] : 0ull;
              or0 |= m0;
              or1 |= m1;
            }
          }
          a0 &= ~or0;
          a1 &= ~or1;
        }
      }
    }
    rowCur = rowN1;
    rowN1 = rowN2;
  }
  __syncthreads();
  for (int r = lane; r < NPOST; r += 64) {
    float4 bx = make_float4(0.f, 0.f, 0.f, 0.f);
    if (r < cnt) bx = *(const float4*)(box6k + ((size_t)b * NPRE + keptIdx[r]) * 4);
    *(float4*)(out + O_ROIS + ((size_t)b * NPOST + r) * 4) = bx;
    out[O_RIDX + b * NPOST + r] = (float)b;
  }
}

extern "C" void kernel_launch(void* const* d_in, const int* in_sizes, int n_in,
                              void* d_out, int out_size, void* d_ws, size_t ws_size,
                              hipStream_t stream) {
  const float* x       = (const float*)d_in[0];
  const float* conv1_w = (const float*)d_in[1];
  const float* conv1_b = (const float*)d_in[2];
  const float* score_w = (const float*)d_in[3];
  const float* score_b = (const float*)d_in[4];
  const float* loc_w   = (const float*)d_in[5];
  const float* loc_b   = (const float*)d_in[6];
  const int* ihp = (const int*)d_in[7];
  const int* iwp = (const int*)d_in[8];
  float* out = (float*)d_out;
  char* ws = (char*)d_ws;
  _Float16* xt1 = (_Float16*)(ws + WO_XT1);
  _Float16* xt2 = (_Float16*)(ws + WO_XT2);
  _Float16* wsBlk = (_Float16*)(ws + WO_WSBLK);
  float* featP = (float*)(ws + WO_FEATP);
  float* wt    = (float*)(ws + WO_WT);
  float* boxes = (float*)(ws + WO_BOXES);
  uint32_t* dkey  = (uint32_t*)(ws + WO_DKEY);
  float* box6k = (float*)(ws + WO_BOX6K);
  unsigned long long* validm = (unsigned long long*)(ws + WO_VALID);
  unsigned long long* mask   = (unsigned long long*)(ws + WO_MASK);

  k_zero<<<2048, 256, 0, stream>>>((u32*)xt1);
  k_xT<<<dim3(8, 50, NB), 256, 0, stream>>>(x, xt1, xt2);
  k_splitw<<<2048, 256, 0, stream>>>(conv1_w, wsBlk);
  k_wt<<<(128 * 56 * 4 + 255) / 256, 256, 0, stream>>>(loc_w, score_w, wt);
  k_conv<<<1408, 128, 0, stream>>>(xt1, xt2, wsBlk, featP);
  k_heads<<<(NB * PIX + 3) / 4, 256, 0, stream>>>(featP, wt, conv1_b, loc_b, score_b,
                                                  ihp, iwp, out, boxes, dkey);
  int topk_lds = 65536 * 2 + 8192 + 512;   // cand + alt + hcnt + small
  hipFuncSetAttribute((const void*)k_topk, hipFuncAttributeMaxDynamicSharedMemorySize,
                      topk_lds);
  k_topk<<<NB, 1024, topk_lds, stream>>>(dkey, boxes, box6k, validm);
  dim3 gm(188, 12, NB);
  k_mask<<<gm, 256, 0, stream>>>(box6k, mask);
  k_scan<<<NB, 64, 0, stream>>>(mask, validm, box6k, out);
}

// Round 17
// 580.269 us; speedup vs baseline: 1.1864x; 1.1864x over previous
//
#include <hip/hip_runtime.h>
#include <stdint.h>

#define NB 4
#define CIN 512
#define PIX 2500
#define KTOT 4608
#define NBOX 22500
#define NPRE 6000
#define NPOST 300
#define NWORD 94
#define SCAP 8192

#define O_LOCS   0
#define O_SCORES 360000
#define O_ROIS   540000
#define O_RIDX   544800
#define O_ANCH   546000

// xT geometry: per image, 64 front-slack + 2704 body + 192 back-slack pixel rows, 512 ch fp16
#define XT_ROWS 2960
#define XT_FRONT 64
#define XT_IMG (XT_ROWS * 512)          // fp16 elements per image
#define XT_SPLIT_BYTES ((size_t)NB * XT_IMG * 2)   // 12,124,160

// workspace offsets (bytes)
#define WO_XT1   0ull
#define WO_XT2   12124160ull
#define WO_WSBLK 24248320ull            // fragment-blocked weights, 9,437,184 B
#define WO_FEATP 33685504ull            // 2 ksplits x 4 b x 2500 p x 512 oc fp32 = 40,960,000
#define WO_WT    74645504ull
#define WO_BOXES 74760192ull
#define WO_DKEY  76200192ull
#define WO_BOX6K 76560192ull
#define WO_VALID 76944192ull
#define WO_MASK  0ull                   // aliases xT (dead after conv)

#define FEATP_HALF 5120000              // floats per ksplit

typedef _Float16 h8 __attribute__((ext_vector_type(8)));
typedef float f32x4 __attribute__((ext_vector_type(4)));
typedef unsigned int u32;
typedef unsigned long long u64;

__device__ __forceinline__ void gll16(const void* g, void* l) {
  __builtin_amdgcn_global_load_lds((const __attribute__((address_space(1))) u32*)g,
                                   (__attribute__((address_space(3))) u32*)l, 16, 0, 0);
}

__device__ __forceinline__ float rd_dim(const int* p) {
  int v = *p;
  if (v > 0 && v < 1000000) return (float)v;
  return __int_as_float(v);
}

// ---------------- zero xT (both splits, incl. slack + borders) --------------
__global__ void k_zero(u32* __restrict__ xt) {
  size_t n = (2 * XT_SPLIT_BYTES) / 4;
  for (size_t i = blockIdx.x * 256ull + threadIdx.x; i < n; i += (size_t)gridDim.x * 256)
    xt[i] = 0u;
}

// ---------------- split + transpose x -> xT[b][pix][ic] fp16 hi/lo ---------
__global__ void k_xT(const float* __restrict__ x, _Float16* __restrict__ x1,
                     _Float16* __restrict__ x2) {
  __shared__ float sx[3200];            // [64 ic][50 c]
  int chunk = blockIdx.x, r0 = blockIdx.y, b = blockIdx.z;
  int t = threadIdx.x;
  int ic0 = chunk * 64;
  for (int i = t; i < 3200; i += 256) {
    int icl = i / 50, c = i - icl * 50;
    sx[i] = x[(((size_t)b * 512 + ic0 + icl) * 50 + r0) * 50 + c];
  }
  __syncthreads();
  for (int j = t; j < 3200; j += 256) {
    int c = j >> 6, icl = j & 63;
    float v = sx[icl * 50 + c];
    _Float16 h1 = (_Float16)v;
    _Float16 h2 = (_Float16)(v - (float)h1);
    size_t dst = (size_t)b * XT_IMG + (size_t)(XT_FRONT + (r0 + 1) * 52 + (c + 1)) * 512 + ic0 + icl;
    x1[dst] = h1;
    x2[dst] = h2;
  }
}

// ---------------- weights -> fragment-blocked split-fp16 -------------------
__global__ void k_splitw(const float* __restrict__ w, _Float16* __restrict__ wblk) {
  int n = 4 * 144 * 16 * 512;
  for (int idx = blockIdx.x * 256 + threadIdx.x; idx < n; idx += gridDim.x * 256) {
    int lane8 = idx & 511;
    int l = lane8 >> 3, j = lane8 & 7;
    int reg = (idx >> 9) & 15;
    int t = idx >> 13;                  // mt*144 + ksI
    int ksI = t % 144, mt = t / 144;
    int ocs = reg >> 1, s = reg & 1;
    int oc = mt * 128 + ocs * 16 + (l & 15);
    int k = ksI * 32 + (l >> 4) * 8 + j;
    int tap = k >> 9, ic = k & 511;
    float v = w[((size_t)oc * 512 + ic) * 9 + tap];
    _Float16 h1 = (_Float16)v;
    wblk[idx] = s ? (_Float16)(v - (float)h1) : h1;
  }
}

// ---------------- pack head weights: wt[(c4*56+j)*4+i] = W[j][c4*4+i] ------
__global__ void k_wt(const float* __restrict__ loc_w, const float* __restrict__ score_w,
                     float* __restrict__ wt) {
  int idx = blockIdx.x * 256 + threadIdx.x;
  if (idx >= 128 * 56 * 4) return;
  int i = idx & 3, j = (idx >> 2) % 56, c4 = idx / 224;
  int c = c4 * 4 + i;
  float v = 0.f;
  if (j < 36) v = loc_w[(size_t)j * 512 + c];
  else if (j < 54) v = score_w[(size_t)(j - 36) * 512 + c];
  wt[idx] = v;
}

// ---------------- conv: A in registers (coalesced global), B dbuf in LDS ---
// (best-known R10/R15 geometry: tile 128x128, grid 704, supertile order)
__global__ __launch_bounds__(128, 2) void k_conv(
    const _Float16* __restrict__ xs1, const _Float16* __restrict__ xs2,
    const _Float16* __restrict__ wsBlk,
    float* __restrict__ featP) {
  __shared__ _Float16 lds[16384];       // 2 bufs x 16 regions x 512 fp16
  int id = blockIdx.x;
  int bz = id & 7;                      // XCD-pinned (b,ks)
  int inner = id >> 3;                  // 0..87
  int st = inner / 44;                  // mt supertile 0..1
  int idx2 = inner - st * 44;           // 0..43
  int nt = idx2 >> 1;
  int mt = st * 2 + (idx2 & 1);
  int b = bz >> 1, ks = bz & 1;
  int t = threadIdx.x, lane = t & 63, w = t >> 6;   // w in {0,1}
  int mb = mt * 128, nb = nt * 128;
  int l15 = lane & 15, l4 = lane >> 4;
  const _Float16* xi1 = xs1 + (size_t)b * XT_IMG + (size_t)XT_FRONT * 512;
  const _Float16* xi2 = xs2 + (size_t)b * XT_IMG + (size_t)XT_FRONT * 512;
  const _Float16* wbase = wsBlk + ((size_t)(mt * 144 + ks * 72) * 16 + w * 8) * 512 + lane * 8;

  f32x4 acc[4][8];                      // [mf][nf]
#pragma unroll
  for (int i = 0; i < 4; i++)
#pragma unroll
    for (int j = 0; j < 8; j++)
      acc[i][j] = (f32x4){0.f, 0.f, 0.f, 0.f};

  auto stageB = [&](int kk, int off) {
    int kg = ks * 2304 + kk * 32;
    int tap = kg >> 9, ic0 = kg & 511;
    int sh = (tap / 3 - 1) * 52 + (tap % 3) - 1;
#pragma unroll
    for (int u = 0; u < 8; u++) {
      int r = w * 8 + u;
      int pxs = r >> 1, s = r & 1;
      const _Float16* xp = s ? xi2 : xi1;
      int qp = nb + pxs * 16 + l15 + sh;
      gll16(xp + (ptrdiff_t)qp * 512 + ic0 + l4 * 8, &lds[off + r * 512]);
    }
  };
  auto loadA = [&](int kk, h8* a) {
    const _Float16* p = wbase + (size_t)kk * 16 * 512;
#pragma unroll
    for (int u = 0; u < 8; u++) a[u] = *(const h8*)(p + u * 512);
  };
  auto compute = [&](int off, const h8* a) {
#pragma unroll
    for (int nf = 0; nf < 8; nf++) {
      h8 b0 = *(const h8*)&lds[off + (nf * 2 + 0) * 512 + lane * 8];
      h8 b1 = *(const h8*)&lds[off + (nf * 2 + 1) * 512 + lane * 8];
      __builtin_amdgcn_s_setprio(1);
#pragma unroll
      for (int mf = 0; mf < 4; mf++) {
        acc[mf][nf] = __builtin_amdgcn_mfma_f32_16x16x32_f16(a[mf * 2 + 0], b0, acc[mf][nf], 0, 0, 0);
        acc[mf][nf] = __builtin_amdgcn_mfma_f32_16x16x32_f16(a[mf * 2 + 0], b1, acc[mf][nf], 0, 0, 0);
        acc[mf][nf] = __builtin_amdgcn_mfma_f32_16x16x32_f16(a[mf * 2 + 1], b0, acc[mf][nf], 0, 0, 0);
      }
      __builtin_amdgcn_s_setprio(0);
    }
  };

  h8 aA[8], aB[8];
  loadA(0, aA);
  stageB(0, 0);
  __syncthreads();                      // buf0 + aA ready
#pragma unroll 1
  for (int kp = 0; kp < 36; kp++) {
    int kk = 2 * kp;
    stageB(kk + 1, 8192);
    loadA(kk + 1, aB);
    compute(0, aA);
    __syncthreads();                    // drain: buf1 + aB landed
    if (kp < 35) {
      stageB(kk + 2, 0);
      loadA(kk + 2, aA);
    }
    compute(8192, aB);
    __syncthreads();
  }

  // C layout (16x16): col = lane&15 (pix), row = (lane>>4)*4 + reg (oc)
  float* fp = featP + (size_t)ks * FEATP_HALF;
#pragma unroll
  for (int nf = 0; nf < 8; nf++) {
    int q = nb + nf * 16 + l15;
    int r = q / 52, c = q - r * 52;
    if (r >= 1 && r <= 50 && c >= 1 && c <= 50) {
      int p = (r - 1) * 50 + (c - 1);
      size_t base = ((size_t)b * PIX + p) * 512;
#pragma unroll
      for (int mf = 0; mf < 4; mf++) {
        int oc0 = mb + w * 64 + mf * 16 + l4 * 4;
        *(float4*)&fp[base + oc0] = make_float4(acc[mf][nf][0], acc[mf][nf][1],
                                                acc[mf][nf][2], acc[mf][nf][3]);
      }
    }
  }
}

// ---------------- heads: LDS-shared weight table (4 pixels/block) ----------
// wt table (114KB) was read per PIXEL (1.1GB L2 traffic). Stage it through
// LDS in 8 chunks of 16 c4-groups (14KB), shared by the block's 4 pixels
// -> wt traffic /4. Accumulation order over c4 unchanged (bit-identical).
// Grid 2500 x 4 waves = exactly 10000 pixels: no early-exit at barriers.
__global__ __launch_bounds__(256) void k_heads(const float* __restrict__ featP,
                                               const float* __restrict__ wt4,
                                               const float* __restrict__ conv_b,
                                               const float* __restrict__ loc_b,
                                               const float* __restrict__ score_b,
                                               const int* __restrict__ ihp,
                                               const int* __restrict__ iwp,
                                               float* __restrict__ out,
                                               float* __restrict__ boxes,
                                               uint32_t* __restrict__ dkey) {
  __shared__ float swt[16 * 56 * 4];    // 14KB: 16 c4-groups x 56 rows x 4
  int wv = threadIdx.x >> 6;
  int wid = blockIdx.x * 4 + wv;        // pixel id, always < 10000
  int lane = threadIdx.x & 63;
  int b = wid / PIX, p = wid % PIX;
  int row = lane < 54 ? lane : 54;
  const float* f0 = featP + ((size_t)b * PIX + p) * 512;
  const float* f1 = f0 + FEATP_HALF;
  float acc = 0.f;
  for (int cc = 0; cc < 8; cc++) {      // 8 chunks of 16 c4-groups
    __syncthreads();                    // prev chunk consumed
    for (int j = threadIdx.x; j < 16 * 224; j += 256)
      swt[j] = wt4[(size_t)cc * 16 * 224 + j];
    __syncthreads();                    // chunk staged
#pragma unroll 4
    for (int cl = 0; cl < 16; cl++) {
      int c4 = cc * 16 + cl;
      float4 u = *(const float4*)(f0 + c4 * 4);
      float4 v = *(const float4*)(f1 + c4 * 4);
      float4 bb = *(const float4*)(conv_b + c4 * 4);
      float4 wvv = *(const float4*)(&swt[(cl * 56 + row) * 4]);
      acc += fmaxf(u.x + v.x + bb.x, 0.f) * wvv.x;
      acc += fmaxf(u.y + v.y + bb.y, 0.f) * wvv.y;
      acc += fmaxf(u.z + v.z + bb.z, 0.f) * wvv.z;
      acc += fmaxf(u.w + v.w + bb.w, 0.f) * wvv.w;
    }
  }
  float bi = 0.f;
  if (lane < 36) bi = loc_b[lane];
  else if (lane < 54) bi = score_b[lane - 36];
  acc += bi;
  if (lane < 36) out[O_LOCS + (size_t)b * 90000 + (size_t)p * 36 + lane] = acc;
  else if (lane < 54) out[O_SCORES + (size_t)b * 45000 + (size_t)p * 18 + (lane - 36)] = acc;

  float imgH = rd_dim(ihp), imgW = rd_dim(iwp);
  int gy = p % 50, gx = p / 50;           // transposed-anchor pairing (meshgrid 'ij')
  float sy = 16.f * gy, sx = 16.f * gx;

  int a9 = (lane < 9) ? lane : 0;
  float dy  = __shfl(acc, a9 * 4 + 0);
  float dxv = __shfl(acc, a9 * 4 + 1);
  float dh  = __shfl(acc, a9 * 4 + 2);
  float dw  = __shfl(acc, a9 * 4 + 3);
  float l0  = __shfl(acc, 36 + a9 * 2);
  float l1  = __shfl(acc, 36 + a9 * 2 + 1);

  {
    float rr = (a9 < 3) ? 0.5f : (a9 < 6 ? 1.f : 2.f);
    int si = a9 % 3;
    float ssc = (si == 0) ? 8.f : (si == 1 ? 16.f : 32.f);
    float hb = 16.f * ssc * sqrtf(rr);
    float wb = 16.f * ssc * sqrtf(1.f / rr);
    float ay1 = (8.f - hb * 0.5f) + sy;
    float ax1 = (8.f - wb * 0.5f) + sx;
    float ay2 = (8.f + hb * 0.5f) + sy;
    float ax2 = (8.f + wb * 0.5f) + sx;
    float h = ay2 - ay1, w2d = ax2 - ax1;
    float cy = ay1 + 0.5f * h, cx = ax1 + 0.5f * w2d;
    float cy2 = dy * h + cy, cx2 = dxv * w2d + cx;
    float h2 = expf(dh) * h, ww2 = expf(dw) * w2d;
    float y1 = cy2 - 0.5f * h2, x1 = cx2 - 0.5f * ww2;
    float y2 = cy2 + 0.5f * h2, x2 = cx2 + 0.5f * ww2;
    y1 = fminf(fmaxf(y1, 0.f), imgH);
    x1 = fminf(fmaxf(x1, 0.f), imgW);
    y2 = fminf(fmaxf(y2, 0.f), imgH);
    x2 = fminf(fmaxf(x2, 0.f), imgW);
    bool valid = (y2 - y1 >= 16.f) && (x2 - x1 >= 16.f);
    float m = fmaxf(l0, l1);
    float e0 = expf(l0 - m), e1 = expf(l1 - m);
    float fg = e1 / (e0 + e1);
    float scv = valid ? fg : -INFINITY;
    if (lane < 9) {
      size_t k = (size_t)b * NBOX + (size_t)p * 9 + a9;
      *(float4*)(boxes + k * 4) = make_float4(y1, x1, y2, x2);
      uint32_t u = __float_as_uint(scv);
      uint32_t f2 = (u >> 31) ? ~u : (u | 0x80000000u);
      dkey[k] = ~f2;   // ascending d == descending score
    }
  }
  if (b == 0 && lane < 36) {
    int aa = lane >> 2, dd = lane & 3;
    float rr2 = (aa < 3) ? 0.5f : (aa < 6 ? 1.f : 2.f);
    int si2 = aa % 3;
    float ss2 = (si2 == 0) ? 8.f : (si2 == 1 ? 16.f : 32.f);
    float hb2 = 16.f * ss2 * sqrtf(rr2);
    float wb2 = 16.f * ss2 * sqrtf(1.f / rr2);
    float v;
    if (dd == 0) v = (8.f - hb2 * 0.5f) + sy;
    else if (dd == 1) v = (8.f - wb2 * 0.5f) + sx;
    else if (dd == 2) v = (8.f + hb2 * 0.5f) + sy;
    else v = (8.f + wb2 * 0.5f) + sx;
    out[O_ANCH + (size_t)p * 36 + lane] = v;
  }
}

// ---------------- exact top-6000: radix-select + index-ordered compaction
//                  + stable 4-bit LDS radix sort (parallel prefix scans) ----
__global__ void k_topk(const uint32_t* __restrict__ dkey, const float* __restrict__ boxes,
                       float* __restrict__ box6k,
                       unsigned long long* __restrict__ validm) {
  extern __shared__ char smem[];
  u64* cand = (u64*)smem;                       // 8192 x u64
  u64* alt  = (u64*)(smem + 65536);             // 8192 x u64 (ping-pong)
  u32* hcnt = (u32*)(smem + 131072);            // [128 units][16 digits]
  u32* wc     = (u32*)(smem + 139264);          // 16 wave counts
  u32* digTot = wc + 16;
  u32* digBase = digTot + 16;
  u32* msc = digBase + 16;                      // scalars
  u32* histw = (u32*)(smem + 65536);            // select-phase [16][256] (aliases alt)
  u32* hist = histw + 4096;                     // [256]
  int b = blockIdx.x, tid = threadIdx.x;
  int wq = tid >> 6, l = tid & 63;
  const uint32_t* dk = dkey + (size_t)b * NBOX;

  // ---- radix-select Dstar (4 byte passes, per-wave histograms) ----
  uint32_t P = 0, need = NPRE;
  for (int pass = 0; pass < 4; pass++) {
    int sh = 24 - 8 * pass;
    for (int i = tid; i < 16 * 256; i += 1024) histw[i] = 0;
    __syncthreads();
    for (int i = tid; i < NBOX; i += 1024) {
      uint32_t d = dk[i];
      bool match = (((uint64_t)d >> (sh + 8)) == ((uint64_t)P >> (sh + 8)));
      if (match) atomicAdd(&histw[wq * 256 + ((d >> sh) & 255u)], 1u);
    }
    __syncthreads();
    for (int bin = tid; bin < 256; bin += 1024) {
      uint32_t s = 0;
#pragma unroll
      for (int q = 0; q < 16; q++) s += histw[q * 256 + bin];
      hist[bin] = s;
    }
    __syncthreads();
    // wave 0: parallel threshold find (v* = first bin with inclusive >= need)
    if (tid < 64) {
      uint32_t h0 = hist[l * 4 + 0], h1 = hist[l * 4 + 1];
      uint32_t h2 = hist[l * 4 + 2], h3 = hist[l * 4 + 3];
      uint32_t p1 = h0, p2 = h0 + h1, p3 = p2 + h2, p4 = p3 + h3;
      uint32_t s = p4;
#pragma unroll
      for (int dd = 1; dd < 64; dd <<= 1) { uint32_t v = __shfl_up(s, dd); if (l >= dd) s += v; }
      uint32_t excl = s - p4;
      uint32_t i0 = excl + p1, i1 = excl + p2, i2 = excl + p3, i3 = excl + p4;
      int local = 4;
      if (i0 >= need) local = 0;
      else if (i1 >= need) local = 1;
      else if (i2 >= need) local = 2;
      else if (i3 >= need) local = 3;
      u64 bal = __ballot(local < 4);
      int lw = bal ? __builtin_ctzll(bal) : 63;
      if (l == lw) {
        if (local < 4) {
          msc[0] = (uint32_t)(l * 4 + local);
          msc[1] = (local == 0) ? excl : (local == 1) ? i0 : (local == 2) ? i1 : i2;
        } else {                        // no crossing: v=255, cum=prefixExcl(255)
          msc[0] = 255u;
          msc[1] = i2;
        }
      }
    }
    __syncthreads();
    need -= msc[1];
    P |= msc[0] << sh;
    __syncthreads();
  }
  uint32_t Dstar = P;

  // ---- index-ordered compaction: cand[] ascending by original index ----
  if (tid == 0) msc[2] = 0;
  __syncthreads();
  for (int c = 0; c < 22; c++) {
    int i = c * 1024 + tid;
    uint32_t d = (i < NBOX) ? dk[i] : 0xFFFFFFFFu;
    bool pred = (i < NBOX) && (d <= Dstar);
    u64 bal = __ballot(pred);
    uint32_t rank = (uint32_t)__popcll(bal & ((1ull << l) - 1ull));
    __syncthreads();                    // prior chunk's wc reads complete
    if (l == 0) wc[wq] = (uint32_t)__popcll(bal);
    __syncthreads();
    if (tid < 64) {                     // wave 0: scan 16 wave counts
      uint32_t v = (l < 16) ? wc[l] : 0u;
      uint32_t s = v;
#pragma unroll
      for (int dd = 1; dd < 16; dd <<= 1) { uint32_t t2 = __shfl_up(s, dd); if (l >= dd) s += t2; }
      uint32_t base0 = msc[2];
      if (l < 16) wc[l] = base0 + s - v;
      if (l == 15) msc[2] = base0 + s;
    }
    __syncthreads();
    if (pred) {
      uint32_t pos = wc[wq] + rank;
      if (pos < SCAP) cand[pos] = ((u64)d << 32) | (uint32_t)i;
    }
  }
  __syncthreads();
  uint32_t cnt = msc[2] < SCAP ? msc[2] : SCAP;
  for (int i = (int)cnt + tid; i < SCAP; i += 1024) cand[i] = ~0ull;
  __syncthreads();

  // ---- stable radix sort on d (8 x 4-bit LSB->MSB); idx order preserved ----
  u64* src = cand;
  u64* dst = alt;
  for (int pass = 0; pass < 8; pass++) {
    int sh = 32 + pass * 4;
    for (int i = tid; i < 2048; i += 1024) hcnt[i] = 0;
    __syncthreads();
    for (int c = 0; c < 8; c++) {
      int i = c * 1024 + tid;
      uint32_t dig = (uint32_t)(src[i] >> sh) & 15u;
      u64 m = ~0ull;
#pragma unroll
      for (int bit = 0; bit < 4; bit++) {
        u64 bb = __ballot((dig >> bit) & 1u);
        m &= ((dig >> bit) & 1u) ? bb : ~bb;
      }
      if (l == __builtin_ctzll(m)) hcnt[(i >> 6) * 16 + dig] = (uint32_t)__popcll(m);
    }
    __syncthreads();
    // wave wq scans digit wq's 128 unit counts (parallel over 16 waves)
    {
      int d = wq;
      uint32_t cl = hcnt[l * 16 + d];
      uint32_t ch = hcnt[(l + 64) * 16 + d];
      uint32_t s = cl;
#pragma unroll
      for (int dd = 1; dd < 64; dd <<= 1) { uint32_t v = __shfl_up(s, dd); if (l >= dd) s += v; }
      uint32_t tl = __shfl(s, 63);
      uint32_t el = s - cl;
      uint32_t s2 = ch;
#pragma unroll
      for (int dd = 1; dd < 64; dd <<= 1) { uint32_t v = __shfl_up(s2, dd); if (l >= dd) s2 += v; }
      uint32_t th = __shfl(s2, 63);
      uint32_t eh = tl + (s2 - ch);
      hcnt[l * 16 + d] = el;
      hcnt[(l + 64) * 16 + d] = eh;
      if (l == 0) digTot[d] = tl + th;
    }
    __syncthreads();
    if (tid == 0) {
      uint32_t basev = 0;
      for (int d2 = 0; d2 < 16; d2++) { digBase[d2] = basev; basev += digTot[d2]; }
    }
    __syncthreads();
    for (int c = 0; c < 8; c++) {
      int i = c * 1024 + tid;
      u64 key = src[i];
      uint32_t dig = (uint32_t)(key >> sh) & 15u;
      u64 m = ~0ull;
#pragma unroll
      for (int bit = 0; bit < 4; bit++) {
        u64 bb = __ballot((dig >> bit) & 1u);
        m &= ((dig >> bit) & 1u) ? bb : ~bb;
      }
      uint32_t rank = (uint32_t)__popcll(m & ((1ull << l) - 1ull));
      uint32_t dpos = digBase[dig] + hcnt[(i >> 6) * 16 + dig] + rank;
      dst[dpos] = key;
    }
    __syncthreads();
    u64* tmp = src; src = dst; dst = tmp;
  }

  for (int r = tid; r < NPRE; r += 1024) {
    u64 kk = cand[r];
    uint32_t idx = (uint32_t)kk;
    float4 bx = *(const float4*)(boxes + ((size_t)b * NBOX + idx) * 4);
    *(float4*)(box6k + ((size_t)b * NPRE + r) * 4) = bx;
  }
  for (int wi = tid; wi < NWORD; wi += 1024) {
    unsigned long long m = 0ull;
    for (int bb = 0; bb < 64; bb++) {
      int r = wi * 64 + bb;
      if (r < NPRE) {
        uint32_t d = (uint32_t)(cand[r] >> 32);
        if (d < 0xFF800000u) m |= (1ull << bb);   // score > -inf
      }
    }
    validm[b * NWORD + wi] = m;
  }
}

// ---------------- NMS suppression bitmask (upper-triangle words only) ------
__global__ __launch_bounds__(256) void k_mask(const float* __restrict__ box6k,
                                              unsigned long long* __restrict__ mask) {
  int b = blockIdx.z, it = blockIdx.x, wt = blockIdx.y;
  int t = threadIdx.x;
  int il = t & 31, wl = t >> 5;
  if (wt * 512 + 511 <= it * 32) return;   // fully below diagonal: never read
  __shared__ float bi[32][4];
  __shared__ float bj[512][4];
  if (t < 128) {
    int ii = it * 32 + (t >> 2);
    if (ii > NPRE - 1) ii = NPRE - 1;
    bi[t >> 2][t & 3] = box6k[((size_t)b * NPRE + ii) * 4 + (t & 3)];
  }
#pragma unroll
  for (int q = 0; q < 2; q++) {
    int v = t + 256 * q;
    int jg = wt * 512 + v;
    float4 f = make_float4(0.f, 0.f, 0.f, 0.f);
    if (jg < NPRE) f = *(const float4*)(box6k + ((size_t)b * NPRE + jg) * 4);
    *(float4*)&bj[v][0] = f;
  }
  __syncthreads();
  int i = it * 32 + il;
  int w = wt * 8 + wl;
  if (i >= NPRE || w >= NWORD) return;
  float y1 = bi[il][0], x1 = bi[il][1], y2 = bi[il][2], x2 = bi[il][3];
  float ar = (y2 - y1) * (x2 - x1);
  unsigned long long m = 0ull;
  int jbase = w * 64;
  for (int jj = 0; jj < 64; jj++) {
    int j = jbase + jj;
    int js = wl * 64 + jj;
    float jy1 = bj[js][0], jx1 = bj[js][1], jy2 = bj[js][2], jx2 = bj[js][3];
    float tlY = fmaxf(y1, jy1), tlX = fmaxf(x1, jx1);
    float brY = fminf(y2, jy2), brX = fminf(x2, jx2);
    float ih = fmaxf(brY - tlY, 0.f), iw2 = fmaxf(brX - tlX, 0.f);
    float inter = ih * iw2;
    float arj = (jy2 - jy1) * (jx2 - jx1);
    float iou = inter / (ar + arj - inter);
    if (iou > 0.7f && j > i && j < NPRE) m |= (1ull << jj);
  }
  mask[((size_t)b * NPRE + i) * NWORD + w] = m;
}

// ---------------- NMS scan: word-aligned windows + 2-deep row prefetch -----
__global__ void k_scan(const unsigned long long* __restrict__ mask,
                       const unsigned long long* __restrict__ validm,
                       const float* __restrict__ box6k, float* __restrict__ out) {
  int b = blockIdx.x;
  int lane = threadIdx.x;               // 64 threads = 1 wave
  const unsigned long long* mb = mask + (size_t)b * NPRE * NWORD;
  u64 a0 = (lane < NWORD) ? validm[b * NWORD + lane] : 0ull;
  u64 a1 = (lane + 64 < NWORD) ? validm[b * NWORD + lane + 64] : 0ull;
  __shared__ int keptIdx[NPOST];
  int cnt = 0;
  bool done = false;
  u64 rowCur = mb[(size_t)lane * NWORD + 0];             // word 0 rows
  u64 rowN1 = mb[(size_t)(64 + lane) * NWORD + 1];       // word 1 rows
  for (int w = 0; w < NWORD && !done; w++) {
    // prefetch word w+2's in-word rows (static, independent of alive chain)
    u64 rowN2 = 0ull;
    if (w + 2 < NWORD) {
      int i2 = (w + 2) * 64 + lane;
      if (i2 < NPRE) rowN2 = mb[(size_t)i2 * NWORD + (w + 2)];
    }
    u64 alive = (w < 64) ? __shfl(a0, w) : __shfl(a1, w - 64);
    if (alive) {
      u64 keep = 0ull;
      while (alive) {
        int q = __builtin_ctzll(alive);
        alive &= alive - 1;
        keep |= (1ull << q);
        if (lane == 0) keptIdx[cnt] = w * 64 + q;
        cnt++;
        if (cnt >= NPOST) { done = true; break; }
        alive &= ~__shfl(rowCur, q);    // forward in-word suppression
      }
      if (w < 64) { if (lane == w) a0 = 0ull; }
      else        { if (lane == w - 64) a1 = 0ull; }
      if (!done) {
        while (keep) {
          u64 or0 = 0ull, or1 = 0ull;
#pragma unroll
          for (int z = 0; z < 8; z++) {
            if (keep) {
              int q = __builtin_ctzll(keep);
              keep &= keep - 1;
              int ki = w * 64 + q;
              u64 m0 = (lane < NWORD && lane > w) ? mb[(size_t)ki * NWORD + lane] : 0ull;
              u64 m1 = (lane + 64 < NWORD && lane + 64 > w) ? mb[(size_t)ki * NWORD + 64 + lane] : 0ull;
              or0 |= m0;
              or1 |= m1;
            }
          }
          a0 &= ~or0;
          a1 &= ~or1;
        }
      }
    }
    rowCur = rowN1;
    rowN1 = rowN2;
  }
  __syncthreads();
  for (int r = lane; r < NPOST; r += 64) {
    float4 bx = make_float4(0.f, 0.f, 0.f, 0.f);
    if (r < cnt) bx = *(const float4*)(box6k + ((size_t)b * NPRE + keptIdx[r]) * 4);
    *(float4*)(out + O_ROIS + ((size_t)b * NPOST + r) * 4) = bx;
    out[O_RIDX + b * NPOST + r] = (float)b;
  }
}

extern "C" void kernel_launch(void* const* d_in, const int* in_sizes, int n_in,
                              void* d_out, int out_size, void* d_ws, size_t ws_size,
                              hipStream_t stream) {
  const float* x       = (const float*)d_in[0];
  const float* conv1_w = (const float*)d_in[1];
  const float* conv1_b = (const float*)d_in[2];
  const float* score_w = (const float*)d_in[3];
  const float* score_b = (const float*)d_in[4];
  const float* loc_w   = (const float*)d_in[5];
  const float* loc_b   = (const float*)d_in[6];
  const int* ihp = (const int*)d_in[7];
  const int* iwp = (const int*)d_in[8];
  float* out = (float*)d_out;
  char* ws = (char*)d_ws;
  _Float16* xt1 = (_Float16*)(ws + WO_XT1);
  _Float16* xt2 = (_Float16*)(ws + WO_XT2);
  _Float16* wsBlk = (_Float16*)(ws + WO_WSBLK);
  float* featP = (float*)(ws + WO_FEATP);
  float* wt    = (float*)(ws + WO_WT);
  float* boxes = (float*)(ws + WO_BOXES);
  uint32_t* dkey  = (uint32_t*)(ws + WO_DKEY);
  float* box6k = (float*)(ws + WO_BOX6K);
  unsigned long long* validm = (unsigned long long*)(ws + WO_VALID);
  unsigned long long* mask   = (unsigned long long*)(ws + WO_MASK);

  k_zero<<<2048, 256, 0, stream>>>((u32*)xt1);
  k_xT<<<dim3(8, 50, NB), 256, 0, stream>>>(x, xt1, xt2);
  k_splitw<<<2048, 256, 0, stream>>>(conv1_w, wsBlk);
  k_wt<<<(128 * 56 * 4 + 255) / 256, 256, 0, stream>>>(loc_w, score_w, wt);
  k_conv<<<704, 128, 0, stream>>>(xt1, xt2, wsBlk, featP);
  k_heads<<<2500, 256, 0, stream>>>(featP, wt, conv1_b, loc_b, score_b,
                                    ihp, iwp, out, boxes, dkey);
  int topk_lds = 65536 * 2 + 8192 + 512;   // cand + alt + hcnt + small
  hipFuncSetAttribute((const void*)k_topk, hipFuncAttributeMaxDynamicSharedMemorySize,
                      topk_lds);
  k_topk<<<NB, 1024, topk_lds, stream>>>(dkey, boxes, box6k, validm);
  dim3 gm(188, 12, NB);
  k_mask<<<gm, 256, 0, stream>>>(box6k, mask);
  k_scan<<<NB, 64, 0, stream>>>(mask, validm, box6k, out);
}